// Round 1
// baseline (1114.147 us; speedup 1.0000x reference)
//
#include <hip/hip_runtime.h>
#include <hip/hip_bf16.h>

#define N_NODES 100000
#define N_EDGES 1600000
#define HID 128
#define OUT_DIM 64
#define N_LAYERS 3

// ---------------- edge canonicalization (int64 vs int32 robustness) --------
__global__ void detect_kernel(const int* __restrict__ raw, int* __restrict__ flag) {
    // int64 layout => odd 32-bit words (high words of values < 2^31) are all 0.
    int is64 = 1;
    for (int i = 1; i < 128; i += 2)
        if (raw[i] != 0) { is64 = 0; break; }
    *flag = is64;
}

__global__ void canon_kernel(const int* __restrict__ raw, const int* __restrict__ flag,
                             int* __restrict__ src, int* __restrict__ dst) {
    int e = blockIdx.x * blockDim.x + threadIdx.x;
    if (e >= N_EDGES) return;
    if (*flag) {
        const long long* r = (const long long*)raw;
        src[e] = (int)r[e];
        dst[e] = (int)r[N_EDGES + e];
    } else {
        src[e] = raw[e];
        dst[e] = raw[N_EDGES + e];
    }
}

// ---------------- CSR build ----------------
__global__ void hist_kernel(const int* __restrict__ dst, int* __restrict__ deg) {
    int e = blockIdx.x * blockDim.x + threadIdx.x;
    if (e < N_EDGES) atomicAdd(&deg[dst[e]], 1);
}

__global__ void scan1_kernel(const int* __restrict__ deg, int* __restrict__ incl,
                             int* __restrict__ bsums, int n) {
    __shared__ int tmp[1024];
    int tid = threadIdx.x;
    int i = blockIdx.x * 1024 + tid;
    int v = (i < n) ? deg[i] : 0;
    tmp[tid] = v;
    __syncthreads();
    for (int off = 1; off < 1024; off <<= 1) {
        int t = (tid >= off) ? tmp[tid - off] : 0;
        __syncthreads();
        tmp[tid] += t;
        __syncthreads();
    }
    if (i < n) incl[i] = tmp[tid];
    if (tid == 1023) bsums[blockIdx.x] = tmp[1023];
}

__global__ void scan2_kernel(int* __restrict__ bsums, int nb) {
    __shared__ int tmp[128];
    int tid = threadIdx.x;
    int v = (tid < nb) ? bsums[tid] : 0;
    tmp[tid] = v;
    __syncthreads();
    for (int off = 1; off < 128; off <<= 1) {
        int t = (tid >= off) ? tmp[tid - off] : 0;
        __syncthreads();
        tmp[tid] += t;
        __syncthreads();
    }
    if (tid < nb) bsums[tid] = tmp[tid] - v;  // exclusive
}

__global__ void scan3_kernel(const int* __restrict__ incl, const int* __restrict__ deg,
                             const int* __restrict__ bsums, int* __restrict__ row_off,
                             float* __restrict__ inv_deg, int n) {
    int i = blockIdx.x * blockDim.x + threadIdx.x;
    if (i < n) {
        row_off[i] = incl[i] - deg[i] + bsums[i >> 10];
        int d = deg[i];
        inv_deg[i] = 1.0f / (float)(d > 0 ? d : 1);
    } else if (i == n) {
        row_off[n] = N_EDGES;
    }
}

__global__ void fill_kernel(const int* __restrict__ src, const int* __restrict__ dst,
                            const int* __restrict__ row_off, int* __restrict__ cursor,
                            int* __restrict__ srcs_sorted) {
    int e = blockIdx.x * blockDim.x + threadIdx.x;
    if (e < N_EDGES) {
        int d = dst[e];
        int p = atomicAdd(&cursor[d], 1);
        srcs_sorted[row_off[d] + p] = src[e];
    }
}

// ---------------- mean aggregation: one block (128 thr) per node ----------
__global__ __launch_bounds__(128) void agg_kernel(
    const float* __restrict__ h, const int* __restrict__ srcs,
    const int* __restrict__ row_off, const float* __restrict__ inv_deg,
    float* __restrict__ meanb) {
    int node = blockIdx.x;
    int c = threadIdx.x;
    __shared__ int s_idx[128];
    int beg = row_off[node], end = row_off[node + 1];
    float acc = 0.f;
    for (int j = beg; j < end; j += 128) {
        int cnt = end - j;
        if (cnt > 128) cnt = 128;
        if (threadIdx.x < cnt) s_idx[threadIdx.x] = srcs[j + threadIdx.x];
        __syncthreads();
        for (int t = 0; t < cnt; ++t)
            acc += h[(size_t)s_idx[t] * HID + c];
        __syncthreads();
    }
    meanb[(size_t)node * HID + c] = acc * inv_deg[node];
}

// ---------------- layer GEMM: H = relu(mean@Wl + h@Wr + b) ----------------
// tile 64 rows x 128 cols, 256 threads, 8x4 outputs/thread, K-chunk 32
__global__ __launch_bounds__(256) void layer_gemm(
    const float* __restrict__ Am, const float* __restrict__ Ah,
    const float* __restrict__ Wl, const float* __restrict__ Wr,
    const float* __restrict__ bias, float* __restrict__ Hout, int n) {
    __shared__ float sAm[32][68];
    __shared__ float sAh[32][68];
    __shared__ float sWl[32][132];
    __shared__ float sWr[32][132];
    int tid = threadIdx.x;
    int cg = tid & 31;   // cols cg*4 .. cg*4+3
    int rg = tid >> 5;   // rows rg*8 .. rg*8+7
    int row0 = blockIdx.x * 64;

    int lr = tid >> 2;   // 0..63 (A-load row)
    int lq = tid & 3;    // 0..3  (A-load k group)
    int arow = row0 + lr;
    if (arow >= n) arow = n - 1;
    int wk = tid >> 3;   // 0..31 (W-load k)
    int wc = tid & 7;    // 0..7  (W-load col group base)

    float acc[8][4];
#pragma unroll
    for (int i = 0; i < 8; ++i)
#pragma unroll
        for (int j = 0; j < 4; ++j) acc[i][j] = 0.f;

    for (int kc = 0; kc < HID; kc += 32) {
        float4 ga0 = *(const float4*)&Am[(size_t)arow * HID + kc + lq * 4];
        float4 ga1 = *(const float4*)&Am[(size_t)arow * HID + kc + (lq + 4) * 4];
        float4 gh0 = *(const float4*)&Ah[(size_t)arow * HID + kc + lq * 4];
        float4 gh1 = *(const float4*)&Ah[(size_t)arow * HID + kc + (lq + 4) * 4];
        float4 gl[4], gr[4];
#pragma unroll
        for (int m = 0; m < 4; ++m) {
            int col = (wc + 8 * m) * 4;
            gl[m] = *(const float4*)&Wl[(size_t)(kc + wk) * HID + col];
            gr[m] = *(const float4*)&Wr[(size_t)(kc + wk) * HID + col];
        }
        __syncthreads();
        {
            const float* p;
            p = (const float*)&ga0;
#pragma unroll
            for (int j = 0; j < 4; ++j) sAm[lq * 4 + j][lr] = p[j];
            p = (const float*)&ga1;
#pragma unroll
            for (int j = 0; j < 4; ++j) sAm[(lq + 4) * 4 + j][lr] = p[j];
            p = (const float*)&gh0;
#pragma unroll
            for (int j = 0; j < 4; ++j) sAh[lq * 4 + j][lr] = p[j];
            p = (const float*)&gh1;
#pragma unroll
            for (int j = 0; j < 4; ++j) sAh[(lq + 4) * 4 + j][lr] = p[j];
#pragma unroll
            for (int m = 0; m < 4; ++m) {
                int col = (wc + 8 * m) * 4;
                *(float4*)&sWl[wk][col] = gl[m];
                *(float4*)&sWr[wk][col] = gr[m];
            }
        }
        __syncthreads();
#pragma unroll 8
        for (int kk = 0; kk < 32; ++kk) {
            float4 am0 = *(const float4*)&sAm[kk][rg * 8];
            float4 am1 = *(const float4*)&sAm[kk][rg * 8 + 4];
            float4 ah0 = *(const float4*)&sAh[kk][rg * 8];
            float4 ah1 = *(const float4*)&sAh[kk][rg * 8 + 4];
            float4 wlv = *(const float4*)&sWl[kk][cg * 4];
            float4 wrv = *(const float4*)&sWr[kk][cg * 4];
            const float* wl = (const float*)&wlv;
            const float* wr = (const float*)&wrv;
            float amv[8], ahv[8];
            *(float4*)&amv[0] = am0; *(float4*)&amv[4] = am1;
            *(float4*)&ahv[0] = ah0; *(float4*)&ahv[4] = ah1;
#pragma unroll
            for (int i = 0; i < 8; ++i) {
#pragma unroll
                for (int j = 0; j < 4; ++j)
                    acc[i][j] += amv[i] * wl[j] + ahv[i] * wr[j];
            }
        }
    }
    float4 bv = *(const float4*)&bias[cg * 4];
    const float* bp = (const float*)&bv;
#pragma unroll
    for (int i = 0; i < 8; ++i) {
        int r = row0 + rg * 8 + i;
        if (r < n) {
            float4 o;
            float* op = (float*)&o;
#pragma unroll
            for (int j = 0; j < 4; ++j) {
                float v = acc[i][j] + bp[j];
                op[j] = v > 0.f ? v : 0.f;
            }
            *(float4*)&Hout[(size_t)r * HID + cg * 4] = o;
        }
    }
}

// ---------------- final FC accumulate: out += H @ Wf (128x64 slice) -------
// tile 128 rows x 64 cols, 256 threads, 8x4 outputs/thread
__global__ __launch_bounds__(256) void fc_accum(
    const float* __restrict__ H, const float* __restrict__ Wf,
    float* __restrict__ out, int n) {
    __shared__ float sHt[32][132];
    __shared__ float sW[32][68];
    int tid = threadIdx.x;
    int cg = tid & 15;   // cols cg*4 .. +3 (64)
    int rg = tid >> 4;   // rows rg*8 .. +7 (128)
    int row0 = blockIdx.x * 128;
    int lr = tid >> 1;   // 0..127
    int lq = tid & 1;
    int arow = row0 + lr;
    if (arow >= n) arow = n - 1;
    int wk = tid >> 3;   // 0..31
    int wc = tid & 7;    // 0..7

    float acc[8][4];
#pragma unroll
    for (int i = 0; i < 8; ++i)
#pragma unroll
        for (int j = 0; j < 4; ++j) acc[i][j] = 0.f;

    for (int kc = 0; kc < HID; kc += 32) {
        float4 gh[4];
#pragma unroll
        for (int m = 0; m < 4; ++m)
            gh[m] = *(const float4*)&H[(size_t)arow * HID + kc + (lq + 2 * m) * 4];
        float4 gw[2];
#pragma unroll
        for (int m = 0; m < 2; ++m)
            gw[m] = *(const float4*)&Wf[(size_t)(kc + wk) * OUT_DIM + (wc + 8 * m) * 4];
        __syncthreads();
#pragma unroll
        for (int m = 0; m < 4; ++m) {
            const float* p = (const float*)&gh[m];
#pragma unroll
            for (int j = 0; j < 4; ++j) sHt[(lq + 2 * m) * 4 + j][lr] = p[j];
        }
#pragma unroll
        for (int m = 0; m < 2; ++m)
            *(float4*)&sW[wk][(wc + 8 * m) * 4] = gw[m];
        __syncthreads();
#pragma unroll 8
        for (int kk = 0; kk < 32; ++kk) {
            float4 h0 = *(const float4*)&sHt[kk][rg * 8];
            float4 h1 = *(const float4*)&sHt[kk][rg * 8 + 4];
            float4 wv = *(const float4*)&sW[kk][cg * 4];
            const float* w = (const float*)&wv;
            float hv[8];
            *(float4*)&hv[0] = h0; *(float4*)&hv[4] = h1;
#pragma unroll
            for (int i = 0; i < 8; ++i)
#pragma unroll
                for (int j = 0; j < 4; ++j)
                    acc[i][j] += hv[i] * w[j];
        }
    }
#pragma unroll
    for (int i = 0; i < 8; ++i) {
        int r = row0 + rg * 8 + i;
        if (r < n) {
            float4 cur = *(const float4*)&out[(size_t)r * OUT_DIM + cg * 4];
            cur.x += acc[i][0];
            cur.y += acc[i][1];
            cur.z += acc[i][2];
            cur.w += acc[i][3];
            *(float4*)&out[(size_t)r * OUT_DIM + cg * 4] = cur;
        }
    }
}

__global__ void init_out(const float* __restrict__ fc_b, float* __restrict__ out) {
    int i = blockIdx.x * blockDim.x + threadIdx.x;
    if (i < N_NODES * OUT_DIM) out[i] = fc_b[i & 63];
}

extern "C" void kernel_launch(void* const* d_in, const int* in_sizes, int n_in,
                              void* d_out, int out_size, void* d_ws, size_t ws_size,
                              hipStream_t stream) {
    const float* x     = (const float*)d_in[0];
    const int*   edges = (const int*)d_in[1];
    const float* Wl    = (const float*)d_in[2];
    const float* Wr    = (const float*)d_in[3];
    const float* b     = (const float*)d_in[4];
    const float* fc_w  = (const float*)d_in[5];
    const float* fc_b  = (const float*)d_in[6];
    float* out = (float*)d_out;

    char* ws = (char*)d_ws;
    size_t off = 0;
    auto alloc = [&](size_t bytes) {
        void* p = ws + off;
        off = (off + bytes + 255) & ~(size_t)255;
        return p;
    };
    int*   flag        = (int*)alloc(256);
    int*   src         = (int*)alloc((size_t)N_EDGES * 4);
    int*   dst         = (int*)alloc((size_t)N_EDGES * 4);
    int*   deg         = (int*)alloc((size_t)N_NODES * 4);
    int*   incl        = (int*)alloc((size_t)N_NODES * 4);
    int*   bsums       = (int*)alloc(128 * 4);
    int*   row_off     = (int*)alloc((size_t)(N_NODES + 1) * 4);
    int*   cursor      = (int*)alloc((size_t)N_NODES * 4);
    float* inv_deg     = (float*)alloc((size_t)N_NODES * 4);
    int*   srcs_sorted = (int*)alloc((size_t)N_EDGES * 4);
    float* meanb       = (float*)alloc((size_t)N_NODES * HID * 4);
    float* hA          = (float*)alloc((size_t)N_NODES * HID * 4);
    float* hB          = (float*)alloc((size_t)N_NODES * HID * 4);

    hipMemsetAsync(deg, 0, (size_t)N_NODES * 4, stream);
    hipMemsetAsync(cursor, 0, (size_t)N_NODES * 4, stream);

    detect_kernel<<<1, 1, 0, stream>>>(edges, flag);
    canon_kernel<<<(N_EDGES + 255) / 256, 256, 0, stream>>>(edges, flag, src, dst);
    hist_kernel<<<(N_EDGES + 255) / 256, 256, 0, stream>>>(dst, deg);
    int nb = (N_NODES + 1023) / 1024;
    scan1_kernel<<<nb, 1024, 0, stream>>>(deg, incl, bsums, N_NODES);
    scan2_kernel<<<1, 128, 0, stream>>>(bsums, nb);
    scan3_kernel<<<(N_NODES + 1 + 255) / 256, 256, 0, stream>>>(incl, deg, bsums, row_off, inv_deg, N_NODES);
    fill_kernel<<<(N_EDGES + 255) / 256, 256, 0, stream>>>(src, dst, row_off, cursor, srcs_sorted);
    init_out<<<(N_NODES * OUT_DIM + 255) / 256, 256, 0, stream>>>(fc_b, out);

    const float* hprev = x;
    float* bufs[2] = {hA, hB};
    for (int l = 0; l < N_LAYERS; ++l) {
        float* hcur = bufs[l & 1];
        agg_kernel<<<N_NODES, 128, 0, stream>>>(hprev, srcs_sorted, row_off, inv_deg, meanb);
        layer_gemm<<<(N_NODES + 63) / 64, 256, 0, stream>>>(
            meanb, hprev, Wl + (size_t)l * HID * HID, Wr + (size_t)l * HID * HID,
            b + (size_t)l * HID, hcur, N_NODES);
        fc_accum<<<(N_NODES + 127) / 128, 256, 0, stream>>>(
            hcur, fc_w + (size_t)l * HID * OUT_DIM, out, N_NODES);
        hprev = hcur;
    }
}

// Round 2
// 689.583 us; speedup vs baseline: 1.6157x; 1.6157x over previous
//
#include <hip/hip_runtime.h>
#include <hip/hip_bf16.h>
#include <stdint.h>

#define N_NODES 100000
#define N_EDGES 1600000
#define HID 128
#define OUT_DIM 64
#define N_LAYERS 3

typedef __attribute__((ext_vector_type(8))) short short8;
typedef __attribute__((ext_vector_type(4))) float v4f;
typedef __attribute__((ext_vector_type(4))) unsigned short ushort4v;

__device__ __forceinline__ float bf2f(unsigned int lo16) {
    union { unsigned int i; float f; } v; v.i = lo16 << 16; return v.f;
}
__device__ __forceinline__ unsigned short f2bf(float f) {
    union { float f; unsigned int i; } v; v.f = f;
    unsigned int r = v.i + 0x7fffu + ((v.i >> 16) & 1u);  // RNE
    return (unsigned short)(r >> 16);
}

// ---------------- edge canonicalization (int64 vs int32 robustness) --------
__global__ void detect_kernel(const int* __restrict__ raw, int* __restrict__ flag) {
    int is64 = 1;
    for (int i = 1; i < 128; i += 2)
        if (raw[i] != 0) { is64 = 0; break; }
    *flag = is64;
}

__global__ void canon_kernel(const int* __restrict__ raw, const int* __restrict__ flag,
                             int* __restrict__ src, int* __restrict__ dst) {
    int e = blockIdx.x * blockDim.x + threadIdx.x;
    if (e >= N_EDGES) return;
    if (*flag) {
        const long long* r = (const long long*)raw;
        src[e] = (int)r[e];
        dst[e] = (int)r[N_EDGES + e];
    } else {
        src[e] = raw[e];
        dst[e] = raw[N_EDGES + e];
    }
}

// ---------------- CSR build ----------------
__global__ void hist_kernel(const int* __restrict__ dst, int* __restrict__ deg) {
    int e = blockIdx.x * blockDim.x + threadIdx.x;
    if (e < N_EDGES) atomicAdd(&deg[dst[e]], 1);
}

__global__ void scan1_kernel(const int* __restrict__ deg, int* __restrict__ incl,
                             int* __restrict__ bsums, int n) {
    __shared__ int tmp[1024];
    int tid = threadIdx.x;
    int i = blockIdx.x * 1024 + tid;
    int v = (i < n) ? deg[i] : 0;
    tmp[tid] = v;
    __syncthreads();
    for (int off = 1; off < 1024; off <<= 1) {
        int t = (tid >= off) ? tmp[tid - off] : 0;
        __syncthreads();
        tmp[tid] += t;
        __syncthreads();
    }
    if (i < n) incl[i] = tmp[tid];
    if (tid == 1023) bsums[blockIdx.x] = tmp[1023];
}

__global__ void scan2_kernel(int* __restrict__ bsums, int nb) {
    __shared__ int tmp[128];
    int tid = threadIdx.x;
    int v = (tid < nb) ? bsums[tid] : 0;
    tmp[tid] = v;
    __syncthreads();
    for (int off = 1; off < 128; off <<= 1) {
        int t = (tid >= off) ? tmp[tid - off] : 0;
        __syncthreads();
        tmp[tid] += t;
        __syncthreads();
    }
    if (tid < nb) bsums[tid] = tmp[tid] - v;  // exclusive
}

__global__ void scan3_kernel(const int* __restrict__ incl, const int* __restrict__ deg,
                             const int* __restrict__ bsums, int* __restrict__ row_off,
                             float* __restrict__ inv_deg, int n) {
    int i = blockIdx.x * blockDim.x + threadIdx.x;
    if (i < n) {
        row_off[i] = incl[i] - deg[i] + bsums[i >> 10];
        int d = deg[i];
        inv_deg[i] = 1.0f / (float)(d > 0 ? d : 1);
    } else if (i == n) {
        row_off[n] = N_EDGES;
    }
}

__global__ void fill_kernel(const int* __restrict__ src, const int* __restrict__ dst,
                            const int* __restrict__ row_off, int* __restrict__ cursor,
                            int* __restrict__ srcs_sorted) {
    int e = blockIdx.x * blockDim.x + threadIdx.x;
    if (e < N_EDGES) {
        int d = dst[e];
        int p = atomicAdd(&cursor[d], 1);
        srcs_sorted[row_off[d] + p] = src[e];
    }
}

// ---------------- weight prep: fp32 -> bf16 transposed -------------------
// WlT/WrT[l][n][k] = W[l][k][n]; fcT[l][o][k] = fc_w[l*HID + k][o]
__global__ void prep_weights(const float* __restrict__ Wl, const float* __restrict__ Wr,
                             const float* __restrict__ fc_w,
                             unsigned short* __restrict__ WlT, unsigned short* __restrict__ WrT,
                             unsigned short* __restrict__ fcT) {
    int idx = blockIdx.x * blockDim.x + threadIdx.x;
    const int WELEMS = N_LAYERS * HID * HID;
    if (idx < WELEMS) {
        int l = idx / (HID * HID);
        int rem = idx - l * HID * HID;
        int k = rem / HID, nn2 = rem - k * HID;
        WlT[l * HID * HID + nn2 * HID + k] = f2bf(Wl[idx]);
        WrT[l * HID * HID + nn2 * HID + k] = f2bf(Wr[idx]);
    } else {
        int j = idx - WELEMS;
        if (j < N_LAYERS * HID * OUT_DIM) {
            int l = j / (HID * OUT_DIM);
            int rem = j - l * HID * OUT_DIM;
            int k = rem / OUT_DIM, o = rem - k * OUT_DIM;
            fcT[l * OUT_DIM * HID + o * HID + k] = f2bf(fc_w[(l * HID + k) * OUT_DIM + o]);
        }
    }
}

// ---------------- x: fp32 -> bf16 ----------------------------------------
__global__ void convert_x(const float* __restrict__ x, unsigned short* __restrict__ xb) {
    int i = blockIdx.x * blockDim.x + threadIdx.x;
    if (i < N_NODES * HID / 4) {
        float4 v = ((const float4*)x)[i];
        ushort4v o;
        o[0] = f2bf(v.x); o[1] = f2bf(v.y); o[2] = f2bf(v.z); o[3] = f2bf(v.w);
        ((ushort4v*)xb)[i] = o;
    }
}

// ---------------- mean aggregation: one wave per node (bf16 h) -----------
__global__ __launch_bounds__(256) void agg_bf(
    const unsigned short* __restrict__ h, const int* __restrict__ srcs,
    const int* __restrict__ row_off, const float* __restrict__ inv_deg,
    unsigned short* __restrict__ meanb) {
    int node = blockIdx.x * 4 + (threadIdx.x >> 6);
    int lane = threadIdx.x & 63;
    if (node >= N_NODES) return;
    int beg = row_off[node], end = row_off[node + 1];
    const uint32_t* h2 = (const uint32_t*)h;
    float ax = 0.f, ay = 0.f;
    int t = beg;
    for (; t + 4 <= end; t += 4) {
        int s0 = srcs[t], s1 = srcs[t + 1], s2 = srcs[t + 2], s3 = srcs[t + 3];
        uint32_t v0 = h2[(size_t)s0 * 64 + lane];
        uint32_t v1 = h2[(size_t)s1 * 64 + lane];
        uint32_t v2 = h2[(size_t)s2 * 64 + lane];
        uint32_t v3 = h2[(size_t)s3 * 64 + lane];
        ax += bf2f(v0 & 0xffffu) + bf2f(v1 & 0xffffu) + bf2f(v2 & 0xffffu) + bf2f(v3 & 0xffffu);
        ay += bf2f(v0 >> 16) + bf2f(v1 >> 16) + bf2f(v2 >> 16) + bf2f(v3 >> 16);
    }
    for (; t < end; ++t) {
        uint32_t v0 = h2[(size_t)srcs[t] * 64 + lane];
        ax += bf2f(v0 & 0xffffu);
        ay += bf2f(v0 >> 16);
    }
    float id = inv_deg[node];
    ax *= id; ay *= id;
    uint32_t packed = (uint32_t)f2bf(ax) | ((uint32_t)f2bf(ay) << 16);
    ((uint32_t*)meanb)[(size_t)node * 64 + lane] = packed;
}

// ---------------- layer: H = relu(mean@Wl + h@Wr + b), bf16 MFMA ---------
// Swapped operands: A-op = W^T[n][k] frags (m-dim = out col), B-op = node rows
// (n-dim = node). D: lane&15 = node, (lane>>4)*4+reg = out col.
__global__ __launch_bounds__(256) void layer_mfma(
    const unsigned short* __restrict__ Am,   // mean, bf16 [node][128]
    const unsigned short* __restrict__ Ah,   // h,    bf16 [node][128]
    const unsigned short* __restrict__ WlT,  // [128 n][128 k] bf16
    const unsigned short* __restrict__ WrT,
    const float* __restrict__ bias,
    unsigned short* __restrict__ Hout, int n) {
    int tid = threadIdx.x;
    int w = tid >> 6, L = tid & 63;
    int q = L >> 4, r16 = L & 15;
    int colbase = (w & 1) * 64;
    int nodebase = (w >> 1) * 64;
    int node0 = blockIdx.x * 128;

    v4f acc[4][4];
#pragma unroll
    for (int i = 0; i < 4; ++i)
#pragma unroll
        for (int j = 0; j < 4; ++j)
#pragma unroll
            for (int r = 0; r < 4; ++r) acc[i][j][r] = 0.f;

    int nd[4];
#pragma unroll
    for (int j = 0; j < 4; ++j) {
        int t = node0 + nodebase + j * 16 + r16;
        nd[j] = t < n ? t : n - 1;
    }

#pragma unroll
    for (int seg = 0; seg < 2; ++seg) {
        const unsigned short* A = seg ? Ah : Am;
        const unsigned short* WT = seg ? WrT : WlT;
#pragma unroll
        for (int t = 0; t < 4; ++t) {
            int koff = t * 32 + q * 8;
            short8 afr[4], bfr[4];
#pragma unroll
            for (int i = 0; i < 4; ++i)
                afr[i] = *(const short8*)&WT[(colbase + i * 16 + r16) * HID + koff];
#pragma unroll
            for (int j = 0; j < 4; ++j)
                bfr[j] = *(const short8*)&A[(size_t)nd[j] * HID + koff];
#pragma unroll
            for (int i = 0; i < 4; ++i)
#pragma unroll
                for (int j = 0; j < 4; ++j)
                    acc[i][j] = __builtin_amdgcn_mfma_f32_16x16x32_bf16(afr[i], bfr[j], acc[i][j], 0, 0, 0);
        }
    }

#pragma unroll
    for (int i = 0; i < 4; ++i) {
        int col = colbase + i * 16 + q * 4;
        float4 bv = *(const float4*)&bias[col];
#pragma unroll
        for (int j = 0; j < 4; ++j) {
            int node = node0 + nodebase + j * 16 + r16;
            if (node < n) {
                float v0 = acc[i][j][0] + bv.x;
                float v1 = acc[i][j][1] + bv.y;
                float v2 = acc[i][j][2] + bv.z;
                float v3 = acc[i][j][3] + bv.w;
                ushort4v o;
                o[0] = f2bf(v0 > 0.f ? v0 : 0.f);
                o[1] = f2bf(v1 > 0.f ? v1 : 0.f);
                o[2] = f2bf(v2 > 0.f ? v2 : 0.f);
                o[3] = f2bf(v3 > 0.f ? v3 : 0.f);
                *(ushort4v*)&Hout[(size_t)node * HID + col] = o;
            }
        }
    }
}

// ---------------- fc accumulate: out (+)= H @ fc_w_l, bf16 MFMA ----------
// Swapped operands again: D lane&15 = node, regs = 4 consecutive out cols.
__global__ __launch_bounds__(256) void fc_mfma(
    const unsigned short* __restrict__ H,    // bf16 [node][128]
    const unsigned short* __restrict__ fcT,  // [64 o][128 k] bf16
    const float* __restrict__ fc_b,
    float* __restrict__ out, int n, int first) {
    int tid = threadIdx.x;
    int w = tid >> 6, L = tid & 63;
    int q = L >> 4, r16 = L & 15;
    int node0 = blockIdx.x * 128 + w * 32;

    int nd[2], valid[2];
#pragma unroll
    for (int j = 0; j < 2; ++j) {
        int t = node0 + j * 16 + r16;
        valid[j] = t < n;
        nd[j] = valid[j] ? t : n - 1;
    }

    v4f acc[4][2];
#pragma unroll
    for (int i = 0; i < 4; ++i) {
        int col = i * 16 + q * 4;
        if (first) {
            float4 bv = *(const float4*)&fc_b[col];
#pragma unroll
            for (int j = 0; j < 2; ++j) {
                acc[i][j][0] = bv.x; acc[i][j][1] = bv.y;
                acc[i][j][2] = bv.z; acc[i][j][3] = bv.w;
            }
        } else {
#pragma unroll
            for (int j = 0; j < 2; ++j)
                acc[i][j] = *(const v4f*)&out[(size_t)nd[j] * OUT_DIM + col];
        }
    }

#pragma unroll
    for (int t = 0; t < 4; ++t) {
        int koff = t * 32 + q * 8;
        short8 afr[4], bfr[2];
#pragma unroll
        for (int i = 0; i < 4; ++i)
            afr[i] = *(const short8*)&fcT[(i * 16 + r16) * HID + koff];
#pragma unroll
        for (int j = 0; j < 2; ++j)
            bfr[j] = *(const short8*)&H[(size_t)nd[j] * HID + koff];
#pragma unroll
        for (int i = 0; i < 4; ++i)
#pragma unroll
            for (int j = 0; j < 2; ++j)
                acc[i][j] = __builtin_amdgcn_mfma_f32_16x16x32_bf16(afr[i], bfr[j], acc[i][j], 0, 0, 0);
    }

#pragma unroll
    for (int i = 0; i < 4; ++i) {
        int col = i * 16 + q * 4;
#pragma unroll
        for (int j = 0; j < 2; ++j) {
            if (valid[j])
                *(v4f*)&out[(size_t)nd[j] * OUT_DIM + col] = acc[i][j];
        }
    }
}

extern "C" void kernel_launch(void* const* d_in, const int* in_sizes, int n_in,
                              void* d_out, int out_size, void* d_ws, size_t ws_size,
                              hipStream_t stream) {
    const float* x     = (const float*)d_in[0];
    const int*   edges = (const int*)d_in[1];
    const float* Wl    = (const float*)d_in[2];
    const float* Wr    = (const float*)d_in[3];
    const float* b     = (const float*)d_in[4];
    const float* fc_w  = (const float*)d_in[5];
    const float* fc_b  = (const float*)d_in[6];
    float* out = (float*)d_out;

    char* ws = (char*)d_ws;
    size_t off = 0;
    auto alloc = [&](size_t bytes) {
        void* p = ws + off;
        off = (off + bytes + 255) & ~(size_t)255;
        return p;
    };
    int*   flag        = (int*)alloc(256);
    int*   src         = (int*)alloc((size_t)N_EDGES * 4);
    int*   dst         = (int*)alloc((size_t)N_EDGES * 4);
    int*   deg         = (int*)alloc((size_t)N_NODES * 4);
    int*   incl        = (int*)alloc((size_t)N_NODES * 4);
    int*   bsums       = (int*)alloc(128 * 4);
    int*   row_off     = (int*)alloc((size_t)(N_NODES + 1) * 4);
    int*   cursor      = (int*)alloc((size_t)N_NODES * 4);
    float* inv_deg     = (float*)alloc((size_t)N_NODES * 4);
    int*   srcs_sorted = (int*)alloc((size_t)N_EDGES * 4);
    unsigned short* xb    = (unsigned short*)alloc((size_t)N_NODES * HID * 2);
    unsigned short* meanb = (unsigned short*)alloc((size_t)N_NODES * HID * 2);
    unsigned short* hA    = (unsigned short*)alloc((size_t)N_NODES * HID * 2);
    unsigned short* hB    = (unsigned short*)alloc((size_t)N_NODES * HID * 2);
    unsigned short* WlT   = (unsigned short*)alloc((size_t)N_LAYERS * HID * HID * 2);
    unsigned short* WrT   = (unsigned short*)alloc((size_t)N_LAYERS * HID * HID * 2);
    unsigned short* fcT   = (unsigned short*)alloc((size_t)N_LAYERS * OUT_DIM * HID * 2);

    hipMemsetAsync(deg, 0, (size_t)N_NODES * 4, stream);
    hipMemsetAsync(cursor, 0, (size_t)N_NODES * 4, stream);

    detect_kernel<<<1, 1, 0, stream>>>(edges, flag);
    canon_kernel<<<(N_EDGES + 255) / 256, 256, 0, stream>>>(edges, flag, src, dst);
    hist_kernel<<<(N_EDGES + 255) / 256, 256, 0, stream>>>(dst, deg);
    int nb = (N_NODES + 1023) / 1024;
    scan1_kernel<<<nb, 1024, 0, stream>>>(deg, incl, bsums, N_NODES);
    scan2_kernel<<<1, 128, 0, stream>>>(bsums, nb);
    scan3_kernel<<<(N_NODES + 1 + 255) / 256, 256, 0, stream>>>(incl, deg, bsums, row_off, inv_deg, N_NODES);
    fill_kernel<<<(N_EDGES + 255) / 256, 256, 0, stream>>>(src, dst, row_off, cursor, srcs_sorted);

    prep_weights<<<(N_LAYERS * HID * HID + N_LAYERS * HID * OUT_DIM + 255) / 256, 256, 0, stream>>>(
        Wl, Wr, fc_w, WlT, WrT, fcT);
    convert_x<<<(N_NODES * HID / 4 + 255) / 256, 256, 0, stream>>>(x, xb);

    const unsigned short* hprev = xb;
    unsigned short* bufs[2] = {hA, hB};
    int ngrid = (N_NODES + 127) / 128;
    for (int l = 0; l < N_LAYERS; ++l) {
        unsigned short* hcur = bufs[l & 1];
        agg_bf<<<(N_NODES + 3) / 4, 256, 0, stream>>>(hprev, srcs_sorted, row_off, inv_deg, meanb);
        layer_mfma<<<ngrid, 256, 0, stream>>>(
            meanb, hprev, WlT + (size_t)l * HID * HID, WrT + (size_t)l * HID * HID,
            b + (size_t)l * HID, hcur, N_NODES);
        fc_mfma<<<ngrid, 256, 0, stream>>>(
            hcur, fcT + (size_t)l * OUT_DIM * HID, fc_b, out, N_NODES, l == 0);
        hprev = hcur;
    }
}